// Round 1
// baseline (1593.673 us; speedup 1.0000x reference)
//
#include <hip/hip_runtime.h>
#include <math.h>

#define S_LEN 2048
#define DMODEL 512
#define NHEAD 8
#define HDIM 64
#define BATCH 4
#define M_ROWS (BATCH * S_LEN)   // 8192

// ---------------------------------------------------------------------------
// Generic tiled fp32 GEMM: C(M,N) = A(M,K) @ W(K,N) + bias, epilogue by MODE
//   MODE 0: plain bias
//   MODE 1: bias + pos[(m % S_LEN)*N + n]      (input projection)
//   MODE 2: relu(bias + acc)                    (FFN1)
//   MODE 3: gate combine: A holds LO (row-stride K/2), A2 holds GO.
//           A_eff[m,k] = k < K/2 ? LO[m,k] : GO[m,k-K/2]
//           g = tanh(relu(acc+bias)); C = g*LO[m,n] + (1-g)*GO[m,n]
// Tiles: BM=BN=64, BK=16, 256 threads, 4x4 per thread. M%64==0, N%64==0, K%16==0.
// ---------------------------------------------------------------------------
template <int MODE>
__global__ __launch_bounds__(256) void gemm_kernel(
    const float* __restrict__ A, const float* __restrict__ A2,
    const float* __restrict__ W, const float* __restrict__ bias,
    const float* __restrict__ pos, float* __restrict__ C,
    int M, int N, int K)
{
    __shared__ float As[16][64 + 4];
    __shared__ float Ws[16][64 + 4];
    const int tid = threadIdx.x;
    const int tx = tid & 15, ty = tid >> 4;
    const int bm = blockIdx.x * 64;
    const int bn = blockIdx.y * 64;
    const int Khalf = K >> 1;
    float acc[4][4] = {};

    for (int k0 = 0; k0 < K; k0 += 16) {
        // A tile -> As[k][m]; each thread loads one float4 (coalesced within rows)
        {
            int f = tid * 4;
            int m = f >> 4;
            int k = f & 15;
            float4 v;
            if (MODE == 3) {
                int kk = k0 + k;                 // tile never spans K/2 (both %16==0)
                const float* base = (kk < Khalf) ? A : A2;
                int kadj = (kk < Khalf) ? kk : (kk - Khalf);
                v = *(const float4*)&base[(size_t)(bm + m) * Khalf + kadj];
            } else {
                v = *(const float4*)&A[(size_t)(bm + m) * K + k0 + k];
            }
            As[k + 0][m] = v.x; As[k + 1][m] = v.y;
            As[k + 2][m] = v.z; As[k + 3][m] = v.w;
        }
        // W tile -> Ws[k][n]
        {
            int f = tid * 4;
            int k = f >> 6;
            int n = f & 63;
            float4 v = *(const float4*)&W[(size_t)(k0 + k) * N + bn + n];
            Ws[k][n + 0] = v.x; Ws[k][n + 1] = v.y;
            Ws[k][n + 2] = v.z; Ws[k][n + 3] = v.w;
        }
        __syncthreads();
#pragma unroll
        for (int kk = 0; kk < 16; ++kk) {
            float a[4], b[4];
#pragma unroll
            for (int i = 0; i < 4; ++i) a[i] = As[kk][ty * 4 + i];
#pragma unroll
            for (int j = 0; j < 4; ++j) b[j] = Ws[kk][tx * 4 + j];
#pragma unroll
            for (int i = 0; i < 4; ++i)
#pragma unroll
                for (int j = 0; j < 4; ++j)
                    acc[i][j] = fmaf(a[i], b[j], acc[i][j]);
        }
        __syncthreads();
    }

#pragma unroll
    for (int i = 0; i < 4; ++i) {
        int m = bm + ty * 4 + i;
#pragma unroll
        for (int j = 0; j < 4; ++j) {
            int n = bn + tx * 4 + j;
            float v = acc[i][j] + bias[n];
            if (MODE == 1) v += pos[(size_t)(m & (S_LEN - 1)) * N + n];
            if (MODE == 2) v = fmaxf(v, 0.0f);
            if (MODE == 3) {
                float g = tanhf(fmaxf(v, 0.0f));
                float lo = A[(size_t)m * Khalf + n];
                float go = A2[(size_t)m * Khalf + n];
                v = g * lo + (1.0f - g) * go;
            }
            C[(size_t)m * N + n] = v;
        }
    }
}

// ---------------------------------------------------------------------------
// Flash-style attention, fp32, 64x64 tiles, online softmax.
// Q,K,V,O: (B, S, D) with head slice at h*HDIM. One block per (q-tile, h, b).
// masked=1: band |q-c| <= 32 (only K-tiles qt-1..qt+1 visited).
// ---------------------------------------------------------------------------
__global__ __launch_bounds__(256) void attn_kernel(
    const float* __restrict__ Q, const float* __restrict__ Kv,
    const float* __restrict__ Vv, float* __restrict__ O, int masked)
{
    __shared__ float Qs[64][64 + 4];  // [d][row]
    __shared__ float Ks[64][64 + 4];  // [d][col]
    __shared__ float Ps[64][64 + 4];  // [col][row]
    __shared__ float Vs[64][64 + 4];  // [col][d]
    const int qt = blockIdx.x, h = blockIdx.y, b = blockIdx.z;
    const int tid = threadIdx.x;
    const int tx = tid & 15, ty = tid >> 4;
    const int lrow = tid >> 2;          // 0..63
    const int dseg = (tid & 3) * 16;    // 0,16,32,48

    {   // load Q tile (transposed into LDS)
        const float* src = Q + ((size_t)(b * S_LEN + qt * 64 + lrow) * DMODEL + h * HDIM + dseg);
#pragma unroll
        for (int e = 0; e < 16; ++e) Qs[dseg + e][lrow] = src[e];
    }

    float m_i[4], l_i[4], Oacc[4][4];
#pragma unroll
    for (int i = 0; i < 4; ++i) {
        m_i[i] = -1e30f; l_i[i] = 0.f;
#pragma unroll
        for (int j = 0; j < 4; ++j) Oacc[i][j] = 0.f;
    }

    int kt_lo = 0, kt_hi = S_LEN / 64 - 1;
    if (masked) {
        kt_lo = max(0, qt * 64 - 32) >> 6;
        kt_hi = min(S_LEN - 1, qt * 64 + 63 + 32) >> 6;
    }

    for (int kt = kt_lo; kt <= kt_hi; ++kt) {
        {
            const float* ksrc = Kv + ((size_t)(b * S_LEN + kt * 64 + lrow) * DMODEL + h * HDIM + dseg);
            const float* vsrc = Vv + ((size_t)(b * S_LEN + kt * 64 + lrow) * DMODEL + h * HDIM + dseg);
#pragma unroll
            for (int e = 0; e < 16; ++e) Ks[dseg + e][lrow] = ksrc[e];
#pragma unroll
            for (int e = 0; e < 4; ++e)
                *(float4*)&Vs[lrow][dseg + e * 4] = *(const float4*)&vsrc[e * 4];
        }
        __syncthreads();   // also covers the Q-tile load on first iteration

        // S-tile = Q @ K^T
        float sacc[4][4] = {};
        for (int d = 0; d < 64; ++d) {
            float a[4], bb[4];
#pragma unroll
            for (int i = 0; i < 4; ++i) a[i] = Qs[d][ty * 4 + i];
#pragma unroll
            for (int j = 0; j < 4; ++j) bb[j] = Ks[d][tx * 4 + j];
#pragma unroll
            for (int i = 0; i < 4; ++i)
#pragma unroll
                for (int j = 0; j < 4; ++j)
                    sacc[i][j] = fmaf(a[i], bb[j], sacc[i][j]);
        }

        // scale + band mask + row max
        float tm[4];
#pragma unroll
        for (int i = 0; i < 4; ++i) {
            float mx = -1e30f;
#pragma unroll
            for (int j = 0; j < 4; ++j) {
                float s = sacc[i][j] * 0.125f;  // 1/sqrt(64)
                if (masked) {
                    int dd = (qt * 64 + ty * 4 + i) - (kt * 64 + tx * 4 + j);
                    if (dd > 32 || dd < -32) s = -1e30f;
                }
                sacc[i][j] = s;
                mx = fmaxf(mx, s);
            }
            tm[i] = mx;
        }
#pragma unroll
        for (int off = 1; off < 16; off <<= 1)
#pragma unroll
            for (int i = 0; i < 4; ++i) tm[i] = fmaxf(tm[i], __shfl_xor(tm[i], off));

        // online softmax update
        float alpha[4], rs[4];
#pragma unroll
        for (int i = 0; i < 4; ++i) {
            float nm = fmaxf(m_i[i], tm[i]);
            alpha[i] = __expf(m_i[i] - nm);
            m_i[i] = nm;
            float r = 0.f;
#pragma unroll
            for (int j = 0; j < 4; ++j) {
                float p = (sacc[i][j] <= -1e29f) ? 0.f : __expf(sacc[i][j] - nm);
                sacc[i][j] = p;
                r += p;
            }
            rs[i] = r;
        }
#pragma unroll
        for (int off = 1; off < 16; off <<= 1)
#pragma unroll
            for (int i = 0; i < 4; ++i) rs[i] += __shfl_xor(rs[i], off);
#pragma unroll
        for (int i = 0; i < 4; ++i) {
            l_i[i] = l_i[i] * alpha[i] + rs[i];
#pragma unroll
            for (int j = 0; j < 4; ++j) Oacc[i][j] *= alpha[i];
        }

        // P -> LDS (transposed for PV product)
#pragma unroll
        for (int i = 0; i < 4; ++i)
#pragma unroll
            for (int j = 0; j < 4; ++j)
                Ps[tx * 4 + j][ty * 4 + i] = sacc[i][j];
        __syncthreads();

        // O += P @ V
        for (int c = 0; c < 64; ++c) {
            float a[4], bb[4];
#pragma unroll
            for (int i = 0; i < 4; ++i) a[i] = Ps[c][ty * 4 + i];
#pragma unroll
            for (int j = 0; j < 4; ++j) bb[j] = Vs[c][tx * 4 + j];
#pragma unroll
            for (int i = 0; i < 4; ++i)
#pragma unroll
                for (int j = 0; j < 4; ++j)
                    Oacc[i][j] = fmaf(a[i], bb[j], Oacc[i][j]);
        }
        __syncthreads();
    }

#pragma unroll
    for (int i = 0; i < 4; ++i) {
        float inv = 1.0f / l_i[i];
        int r = qt * 64 + ty * 4 + i;
#pragma unroll
        for (int j = 0; j < 4; ++j)
            O[(size_t)(b * S_LEN + r) * DMODEL + h * HDIM + tx * 4 + j] = Oacc[i][j] * inv;
    }
}

// ---------------------------------------------------------------------------
// LayerNorm kernels: one wave (64 lanes) per row of 512.
// ---------------------------------------------------------------------------
__device__ inline float wave_sum64(float v) {
#pragma unroll
    for (int off = 1; off < 64; off <<= 1) v += __shfl_xor(v, off);
    return v;
}

__global__ __launch_bounds__(64) void ln_res_kernel(
    const float* __restrict__ A, const float* __restrict__ Bb,
    const float* __restrict__ g, const float* __restrict__ be,
    float* __restrict__ out)
{
    const size_t row = blockIdx.x;
    const int lane = threadIdx.x;
    float x[8]; float s = 0.f;
#pragma unroll
    for (int k = 0; k < 8; ++k) {
        size_t idx = row * DMODEL + k * 64 + lane;
        x[k] = A[idx] + Bb[idx];
        s += x[k];
    }
    s = wave_sum64(s);
    float mean = s * (1.0f / DMODEL);
    float v = 0.f;
#pragma unroll
    for (int k = 0; k < 8; ++k) { float d = x[k] - mean; v += d * d; }
    v = wave_sum64(v) * (1.0f / DMODEL);
    float r = rsqrtf(v + 1e-5f);
#pragma unroll
    for (int k = 0; k < 8; ++k)
        out[row * DMODEL + k * 64 + lane] = (x[k] - mean) * r * g[k * 64 + lane] + be[k * 64 + lane];
}

// h = LN(LN(A+Bb, g2,b2), g3,b3)
__global__ __launch_bounds__(64) void ln_double_kernel(
    const float* __restrict__ A, const float* __restrict__ Bb,
    const float* __restrict__ g2, const float* __restrict__ b2,
    const float* __restrict__ g3, const float* __restrict__ b3,
    float* __restrict__ out)
{
    const size_t row = blockIdx.x;
    const int lane = threadIdx.x;
    float x[8]; float s = 0.f;
#pragma unroll
    for (int k = 0; k < 8; ++k) {
        size_t idx = row * DMODEL + k * 64 + lane;
        x[k] = A[idx] + Bb[idx];
        s += x[k];
    }
    s = wave_sum64(s);
    float mean = s * (1.0f / DMODEL);
    float v = 0.f;
#pragma unroll
    for (int k = 0; k < 8; ++k) { float d = x[k] - mean; v += d * d; }
    v = wave_sum64(v) * (1.0f / DMODEL);
    float r = rsqrtf(v + 1e-5f);
    float t[8]; float s2 = 0.f;
#pragma unroll
    for (int k = 0; k < 8; ++k) {
        t[k] = (x[k] - mean) * r * g2[k * 64 + lane] + b2[k * 64 + lane];
        s2 += t[k];
    }
    s2 = wave_sum64(s2);
    float mean2 = s2 * (1.0f / DMODEL);
    float v2 = 0.f;
#pragma unroll
    for (int k = 0; k < 8; ++k) { float d = t[k] - mean2; v2 += d * d; }
    v2 = wave_sum64(v2) * (1.0f / DMODEL);
    float r2 = rsqrtf(v2 + 1e-5f);
#pragma unroll
    for (int k = 0; k < 8; ++k)
        out[row * DMODEL + k * 64 + lane] = (t[k] - mean2) * r2 * g3[k * 64 + lane] + b3[k * 64 + lane];
}

// ---------------------------------------------------------------------------
// Mean-pool over S (partial sums + atomics), then tiny final GEMM.
// ---------------------------------------------------------------------------
__global__ __launch_bounds__(256) void pool_kernel(
    const float* __restrict__ h2, float* __restrict__ pooled)
{
    const int b = blockIdx.x >> 4;
    const int chunk = blockIdx.x & 15;
    const int tid = threadIdx.x;
    float s0 = 0.f, s1 = 0.f;
    size_t base = (size_t)(b * S_LEN + chunk * 128) * DMODEL;
    for (int r = 0; r < 128; ++r) {
        s0 += h2[base + (size_t)r * DMODEL + tid];
        s1 += h2[base + (size_t)r * DMODEL + 256 + tid];
    }
    atomicAdd(&pooled[b * DMODEL + tid], s0);
    atomicAdd(&pooled[b * DMODEL + 256 + tid], s1);
}

__global__ __launch_bounds__(128) void out_kernel(
    const float* __restrict__ pooled, const float* __restrict__ w,
    const float* __restrict__ bias, float* __restrict__ out)
{
    const int b = blockIdx.x;
    const int o = threadIdx.x;
    float acc = 0.f;
    for (int d = 0; d < DMODEL; ++d)
        acc += pooled[b * DMODEL + d] * w[d * 128 + o];
    out[b * 128 + o] = acc * (1.0f / S_LEN) + bias[o];
}

// ---------------------------------------------------------------------------
extern "C" void kernel_launch(void* const* d_in, const int* in_sizes, int n_in,
                              void* d_out, int out_size, void* d_ws, size_t ws_size,
                              hipStream_t stream)
{
    const float* x      = (const float*)d_in[0];
    const float* pos    = (const float*)d_in[1];
    const float* win_w  = (const float*)d_in[2];
    const float* win_b  = (const float*)d_in[3];
    const float* l_wqkv = (const float*)d_in[4];
    const float* l_bqkv = (const float*)d_in[5];
    const float* l_wo   = (const float*)d_in[6];
    const float* l_bo   = (const float*)d_in[7];
    const float* g_wqkv = (const float*)d_in[8];
    const float* g_bqkv = (const float*)d_in[9];
    const float* g_wo   = (const float*)d_in[10];
    const float* g_bo   = (const float*)d_in[11];
    const float* gate_w = (const float*)d_in[12];
    const float* gate_b = (const float*)d_in[13];
    const float* ffn_w1 = (const float*)d_in[14];
    const float* ffn_b1 = (const float*)d_in[15];
    const float* ffn_w2 = (const float*)d_in[16];
    const float* ffn_b2 = (const float*)d_in[17];
    const float* n1_g   = (const float*)d_in[18];
    const float* n1_b   = (const float*)d_in[19];
    const float* n2_g   = (const float*)d_in[20];
    const float* n2_b   = (const float*)d_in[21];
    const float* n3_g   = (const float*)d_in[22];
    const float* n3_b   = (const float*)d_in[23];
    const float* out_w  = (const float*)d_in[24];
    const float* out_b  = (const float*)d_in[25];
    float* out = (float*)d_out;

    // workspace pool: 6 units of M*D fp32 (96 MiB total), aggressively reused
    float* ws = (float*)d_ws;
    const size_t U = (size_t)M_ROWS * DMODEL;
    float* H   = ws + 0 * U;
    float* Qb  = ws + 1 * U;
    float* Kb  = ws + 2 * U;
    float* Vb  = ws + 3 * U;
    float* AO  = ws + 4 * U;
    float* LO  = ws + 5 * U;
    float* GO     = Qb;   // Q dead after global attention
    float* FUSED  = Kb;   // K dead after global attention
    float* H1     = Vb;   // V dead after global attention
    float* FFNMID = AO;   // spans units 4..5 (AO+LO), both dead after gate
    float* FFNOUT = Qb;   // GO dead after gate
    float* H2     = Kb;   // FUSED dead after LN1
    float* POOLED = H;    // H dead after LN1

    dim3 blk(256);
    dim3 gD(M_ROWS / 64, 512 / 64);    // N=512 GEMMs
    dim3 gF(M_ROWS / 64, 1024 / 64);   // N=1024 GEMM

    // h = x @ win_w + win_b + pos
    gemm_kernel<1><<<gD, blk, 0, stream>>>(x, nullptr, win_w, win_b, pos, H, M_ROWS, 512, 256);

    // local path
    gemm_kernel<0><<<gD, blk, 0, stream>>>(H, nullptr, l_wqkv + 0 * 512 * 512, l_bqkv + 0 * 512, nullptr, Qb, M_ROWS, 512, 512);
    gemm_kernel<0><<<gD, blk, 0, stream>>>(H, nullptr, l_wqkv + 1 * 512 * 512, l_bqkv + 1 * 512, nullptr, Kb, M_ROWS, 512, 512);
    gemm_kernel<0><<<gD, blk, 0, stream>>>(H, nullptr, l_wqkv + 2 * 512 * 512, l_bqkv + 2 * 512, nullptr, Vb, M_ROWS, 512, 512);
    attn_kernel<<<dim3(S_LEN / 64, NHEAD, BATCH), blk, 0, stream>>>(Qb, Kb, Vb, AO, 1);
    gemm_kernel<0><<<gD, blk, 0, stream>>>(AO, nullptr, l_wo, l_bo, nullptr, LO, M_ROWS, 512, 512);

    // global path
    gemm_kernel<0><<<gD, blk, 0, stream>>>(H, nullptr, g_wqkv + 0 * 512 * 512, g_bqkv + 0 * 512, nullptr, Qb, M_ROWS, 512, 512);
    gemm_kernel<0><<<gD, blk, 0, stream>>>(H, nullptr, g_wqkv + 1 * 512 * 512, g_bqkv + 1 * 512, nullptr, Kb, M_ROWS, 512, 512);
    gemm_kernel<0><<<gD, blk, 0, stream>>>(H, nullptr, g_wqkv + 2 * 512 * 512, g_bqkv + 2 * 512, nullptr, Vb, M_ROWS, 512, 512);
    attn_kernel<<<dim3(S_LEN / 64, NHEAD, BATCH), blk, 0, stream>>>(Qb, Kb, Vb, AO, 0);
    gemm_kernel<0><<<gD, blk, 0, stream>>>(AO, nullptr, g_wo, g_bo, nullptr, GO, M_ROWS, 512, 512);

    // gate + fuse (fused epilogue, no materialized concat)
    gemm_kernel<3><<<gD, blk, 0, stream>>>(LO, GO, gate_w, gate_b, nullptr, FUSED, M_ROWS, 512, 1024);

    // h1 = LN(h + fused)
    ln_res_kernel<<<M_ROWS, 64, 0, stream>>>(H, FUSED, n1_g, n1_b, H1);

    // FFN
    gemm_kernel<2><<<gF, blk, 0, stream>>>(H1, nullptr, ffn_w1, ffn_b1, nullptr, FFNMID, M_ROWS, 1024, 512);
    gemm_kernel<0><<<gD, blk, 0, stream>>>(FFNMID, nullptr, ffn_w2, ffn_b2, nullptr, FFNOUT, M_ROWS, 512, 1024);

    // h2 = LN(LN(h1 + ffn, n2), n3)
    ln_double_kernel<<<M_ROWS, 64, 0, stream>>>(H1, FFNOUT, n2_g, n2_b, n3_g, n3_b, H2);

    // mean-pool over S, then final projection
    hipMemsetAsync(POOLED, 0, BATCH * DMODEL * sizeof(float), stream);
    pool_kernel<<<dim3(BATCH * 16), blk, 0, stream>>>(H2, POOLED);
    out_kernel<<<dim3(BATCH), dim3(128), 0, stream>>>(POOLED, out_w, out_b, out);
}

// Round 2
// 494.290 us; speedup vs baseline: 3.2242x; 3.2242x over previous
//
#include <hip/hip_runtime.h>
#include <math.h>

#define S_LEN 2048
#define DMODEL 512
#define NHEAD 8
#define BATCH 4
#define M_ROWS (BATCH * S_LEN)   // 8192

typedef __attribute__((ext_vector_type(8))) short frag8;   // 8 bf16 (4 VGPRs)
typedef __attribute__((ext_vector_type(4))) float f32x4;   // MFMA accumulator

__device__ inline unsigned short f2bf(float f) {
    unsigned int u = __float_as_uint(f);
    return (unsigned short)((u + 0x7FFFu + ((u >> 16) & 1u)) >> 16);  // RNE
}
__device__ inline float bf2f(unsigned short h) {
    return __uint_as_float(((unsigned int)h) << 16);
}

// ---------------------------------------------------------------------------
// Weight transpose + cast: W(K,N) fp32 -> Wt(N,K) bf16.  grid (K/32, N/32, batch)
// ---------------------------------------------------------------------------
__global__ __launch_bounds__(256) void wcast_kernel(
    const float* __restrict__ W, unsigned short* __restrict__ Wt, int K, int N)
{
    __shared__ float t[32][33];
    const int k0 = blockIdx.x * 32, n0 = blockIdx.y * 32;
    const float* Wb = W + (size_t)blockIdx.z * K * N;
    unsigned short* Wtb = Wt + (size_t)blockIdx.z * K * N;
    {
        int kk = threadIdx.x >> 3, nq = (threadIdx.x & 7) * 4;
        float4 v = *(const float4*)&Wb[(size_t)(k0 + kk) * N + n0 + nq];
        t[kk][nq + 0] = v.x; t[kk][nq + 1] = v.y; t[kk][nq + 2] = v.z; t[kk][nq + 3] = v.w;
    }
    __syncthreads();
    {
        int n = threadIdx.x >> 3, kq = (threadIdx.x & 7) * 4;
        ushort4 o;
        o.x = f2bf(t[kq + 0][n]); o.y = f2bf(t[kq + 1][n]);
        o.z = f2bf(t[kq + 2][n]); o.w = f2bf(t[kq + 3][n]);
        *(ushort4*)&Wtb[(size_t)(n0 + n) * K + k0 + kq] = o;
    }
}

// ---------------------------------------------------------------------------
// MFMA GEMM: C(M,N) bf16 = A(M,K) @ Wt(N,K)^T + bias(fp32), epilogue by MODE.
//   MODE 0: bias            MODE 1: bias + pos  (A is fp32)
//   MODE 2: relu(bias+acc)  MODE 3: gate blend (A=LO bf16, A2=GO bf16, K=1024)
// BM=128, BN=64, BK=64; 256 threads = 4 waves; wave tile 64x32 (4x2 MFMA tiles).
// ---------------------------------------------------------------------------
template <int MODE>
__global__ __launch_bounds__(256) void gemm_mfma(
    const void* __restrict__ Av, const unsigned short* __restrict__ A2,
    const unsigned short* __restrict__ Wt, const float* __restrict__ bias,
    const float* __restrict__ pos, unsigned short* __restrict__ C,
    int M, int N, int K)
{
    __shared__ unsigned short As[128][72];   // [m][k], stride 144 B (16B-aligned)
    __shared__ unsigned short Bs[64][72];    // [n][k]
    const int tid = threadIdx.x;
    const int wave = tid >> 6, lane = tid & 63;
    const int lr = lane & 15, quad = lane >> 4, q8 = quad * 8;
    const int bm = blockIdx.x * 128, bn = blockIdx.y * 64;
    const int rm = (wave >> 1) * 64, rn = (wave & 1) * 32;
    const int Khalf = K >> 1;

    f32x4 acc[4][2];
#pragma unroll
    for (int t = 0; t < 4; ++t)
#pragma unroll
        for (int u = 0; u < 2; ++u) acc[t][u] = (f32x4){0.f, 0.f, 0.f, 0.f};

    for (int k0 = 0; k0 < K; k0 += 64) {
        __syncthreads();
        // ---- stage A tile (128 x 64) ----
        {
            const int m = tid >> 1, kh = (tid & 1) * 32;
            if constexpr (MODE == 1) {
                const float* src = (const float*)Av + (size_t)(bm + m) * K + k0 + kh;
#pragma unroll
                for (int i = 0; i < 4; ++i) {
                    float4 v0 = *(const float4*)(src + i * 8);
                    float4 v1 = *(const float4*)(src + i * 8 + 4);
                    unsigned short us[8];
                    us[0] = f2bf(v0.x); us[1] = f2bf(v0.y); us[2] = f2bf(v0.z); us[3] = f2bf(v0.w);
                    us[4] = f2bf(v1.x); us[5] = f2bf(v1.y); us[6] = f2bf(v1.z); us[7] = f2bf(v1.w);
                    *(uint4*)&As[m][kh + i * 8] = *(uint4*)us;
                }
            } else {
                const unsigned short* Ab = (const unsigned short*)Av;
                const int kk = k0 + kh;
                const unsigned short* src;
                if constexpr (MODE == 3)
                    src = (kk < Khalf) ? Ab + (size_t)(bm + m) * Khalf + kk
                                       : A2 + (size_t)(bm + m) * Khalf + (kk - Khalf);
                else
                    src = Ab + (size_t)(bm + m) * K + kk;
#pragma unroll
                for (int i = 0; i < 4; ++i)
                    *(uint4*)&As[m][kh + i * 8] = *(const uint4*)(src + i * 8);
            }
        }
        // ---- stage B tile (64 n x 64 k) from Wt[n][k] ----
        {
            const int n = tid >> 2, kq = (tid & 3) * 16;
            const unsigned short* src = Wt + (size_t)(bn + n) * K + k0 + kq;
            *(uint4*)&Bs[n][kq] = *(const uint4*)src;
            *(uint4*)&Bs[n][kq + 8] = *(const uint4*)(src + 8);
        }
        __syncthreads();
        // ---- MFMA: 2 k-chunks of 32 ----
#pragma unroll
        for (int kc = 0; kc < 2; ++kc) {
            frag8 af[4], bfr[2];
#pragma unroll
            for (int t = 0; t < 4; ++t)
                af[t] = *(const frag8*)&As[rm + t * 16 + lr][kc * 32 + q8];
#pragma unroll
            for (int u = 0; u < 2; ++u)
                bfr[u] = *(const frag8*)&Bs[rn + u * 16 + lr][kc * 32 + q8];
#pragma unroll
            for (int t = 0; t < 4; ++t)
#pragma unroll
                for (int u = 0; u < 2; ++u)
                    acc[t][u] = __builtin_amdgcn_mfma_f32_16x16x32_bf16(
                        af[t], bfr[u], acc[t][u], 0, 0, 0);
        }
    }

    // ---- epilogue ----
#pragma unroll
    for (int t = 0; t < 4; ++t) {
#pragma unroll
        for (int i = 0; i < 4; ++i) {
            const int m = bm + rm + t * 16 + quad * 4 + i;
#pragma unroll
            for (int u = 0; u < 2; ++u) {
                const int n = bn + rn + u * 16 + lr;
                float v = acc[t][u][i] + bias[n];
                if constexpr (MODE == 1) v += pos[(size_t)(m & (S_LEN - 1)) * N + n];
                if constexpr (MODE == 2) v = fmaxf(v, 0.0f);
                if constexpr (MODE == 3) {
                    float g = tanhf(fmaxf(v, 0.0f));
                    float lo = bf2f(((const unsigned short*)Av)[(size_t)m * Khalf + n]);
                    float go = bf2f(A2[(size_t)m * Khalf + n]);
                    v = g * lo + (1.0f - g) * go;
                }
                C[(size_t)m * N + n] = f2bf(v);
            }
        }
    }
}

// ---------------------------------------------------------------------------
// MFMA flash attention. Q,K,V,O: (B,S,D) bf16, head slice h*64. 64x64 tiles.
// Block = 256 thr = 4 waves; wave handles 16 q-rows. masked: band |q-c|<=32.
// ---------------------------------------------------------------------------
__global__ __launch_bounds__(256) void attn_mfma(
    const unsigned short* __restrict__ Q, const unsigned short* __restrict__ Kv,
    const unsigned short* __restrict__ Vv, unsigned short* __restrict__ O, int masked)
{
    __shared__ unsigned short Qs[64][72];   // [q][d]
    __shared__ unsigned short Ks[64][72];   // [c][d]
    __shared__ unsigned short Vts[64][72];  // [d][c]
    __shared__ unsigned short Ps[64][72];   // [q][c]
    const int qt = blockIdx.x, h = blockIdx.y, b = blockIdx.z;
    const int tid = threadIdx.x;
    const int wave = tid >> 6, lane = tid & 63;
    const int lr = lane & 15, quad = lane >> 4, q8 = quad * 8;

    {   // Q tile: each wave stages exactly its own 16 rows (no barrier needed)
        const int q = tid >> 2, d0 = (tid & 3) * 16;
        const unsigned short* src = Q + ((size_t)(b * S_LEN + qt * 64 + q) * DMODEL + h * 64 + d0);
        *(uint4*)&Qs[q][d0] = *(const uint4*)src;
        *(uint4*)&Qs[q][d0 + 8] = *(const uint4*)(src + 8);
    }

    f32x4 oacc[4];
#pragma unroll
    for (int t = 0; t < 4; ++t) oacc[t] = (f32x4){0.f, 0.f, 0.f, 0.f};
    float m_i[4] = {-1e30f, -1e30f, -1e30f, -1e30f};
    float l_i[4] = {0.f, 0.f, 0.f, 0.f};

    int kt0 = 0, kt1 = S_LEN / 64 - 1;
    if (masked) { kt0 = qt > 0 ? qt - 1 : 0; kt1 = qt < 31 ? qt + 1 : 31; }

    for (int kt = kt0; kt <= kt1; ++kt) {
        __syncthreads();
        {   // stage K (as [c][d]) and V transposed (as [d][c])
            const int c = tid >> 2, d0 = (tid & 3) * 16;
            const unsigned short* ksrc = Kv + ((size_t)(b * S_LEN + kt * 64 + c) * DMODEL + h * 64 + d0);
            *(uint4*)&Ks[c][d0] = *(const uint4*)ksrc;
            *(uint4*)&Ks[c][d0 + 8] = *(const uint4*)(ksrc + 8);
            const unsigned short* vsrc = Vv + ((size_t)(b * S_LEN + kt * 64 + c) * DMODEL + h * 64 + d0);
            unsigned short vb[16];
            *(uint4*)&vb[0] = *(const uint4*)vsrc;
            *(uint4*)&vb[8] = *(const uint4*)(vsrc + 8);
#pragma unroll
            for (int j = 0; j < 16; ++j) Vts[d0 + j][c] = vb[j];
        }
        __syncthreads();

        // ---- S = Q K^T ----
        f32x4 sacc[4];
#pragma unroll
        for (int t = 0; t < 4; ++t) sacc[t] = (f32x4){0.f, 0.f, 0.f, 0.f};
#pragma unroll
        for (int kc = 0; kc < 2; ++kc) {
            frag8 a = *(const frag8*)&Qs[wave * 16 + lr][kc * 32 + q8];
#pragma unroll
            for (int t = 0; t < 4; ++t) {
                frag8 bb = *(const frag8*)&Ks[t * 16 + lr][kc * 32 + q8];
                sacc[t] = __builtin_amdgcn_mfma_f32_16x16x32_bf16(a, bb, sacc[t], 0, 0, 0);
            }
        }

        // ---- online softmax (fp32), write P (bf16) to LDS ----
#pragma unroll
        for (int i = 0; i < 4; ++i) {
            float s[4];
#pragma unroll
            for (int t = 0; t < 4; ++t) s[t] = sacc[t][i] * 0.125f;
            if (masked) {
                const int qa = qt * 64 + wave * 16 + quad * 4 + i;
                const int ca = kt * 64 + lr;
#pragma unroll
                for (int t = 0; t < 4; ++t) {
                    int d = qa - (ca + t * 16);
                    if (d > 32 || d < -32) s[t] = -1e30f;
                }
            }
            float mx = fmaxf(fmaxf(s[0], s[1]), fmaxf(s[2], s[3]));
#pragma unroll
            for (int off = 1; off < 16; off <<= 1) mx = fmaxf(mx, __shfl_xor(mx, off));
            const float nm = fmaxf(m_i[i], mx);
            const float al = __expf(m_i[i] - nm);
            float p[4], rs = 0.f;
#pragma unroll
            for (int t = 0; t < 4; ++t) {
                p[t] = (s[t] <= -1e29f) ? 0.f : __expf(s[t] - nm);
                rs += p[t];
            }
#pragma unroll
            for (int off = 1; off < 16; off <<= 1) rs += __shfl_xor(rs, off);
            l_i[i] = l_i[i] * al + rs;
            m_i[i] = nm;
#pragma unroll
            for (int t = 0; t < 4; ++t) {
                oacc[t][i] *= al;
                Ps[wave * 16 + quad * 4 + i][t * 16 + lr] = f2bf(p[t]);
            }
        }
        __syncthreads();   // conservative: order Ps writes before frag reads

        // ---- O += P V ----
#pragma unroll
        for (int cc = 0; cc < 2; ++cc) {
            frag8 a = *(const frag8*)&Ps[wave * 16 + lr][cc * 32 + q8];
#pragma unroll
            for (int t = 0; t < 4; ++t) {
                frag8 bb = *(const frag8*)&Vts[t * 16 + lr][cc * 32 + q8];
                oacc[t] = __builtin_amdgcn_mfma_f32_16x16x32_bf16(a, bb, oacc[t], 0, 0, 0);
            }
        }
    }

    // ---- epilogue ----
#pragma unroll
    for (int i = 0; i < 4; ++i) {
        const float inv = 1.0f / l_i[i];
        const int q = qt * 64 + wave * 16 + quad * 4 + i;
#pragma unroll
        for (int t = 0; t < 4; ++t)
            O[(size_t)(b * S_LEN + q) * DMODEL + h * 64 + t * 16 + lr] = f2bf(oacc[t][i] * inv);
    }
}

// ---------------------------------------------------------------------------
// LayerNorm (bf16 in/out, fp32 math): one wave per row of 512.
// ---------------------------------------------------------------------------
__device__ inline float wave_sum64(float v) {
#pragma unroll
    for (int off = 1; off < 64; off <<= 1) v += __shfl_xor(v, off);
    return v;
}

__global__ __launch_bounds__(64) void ln_res_kernel(
    const unsigned short* __restrict__ A, const unsigned short* __restrict__ Bb,
    const float* __restrict__ g, const float* __restrict__ be,
    unsigned short* __restrict__ out)
{
    const size_t row = blockIdx.x;
    const int lane = threadIdx.x;
    float x[8]; float s = 0.f;
#pragma unroll
    for (int k = 0; k < 8; ++k) {
        size_t idx = row * DMODEL + k * 64 + lane;
        x[k] = bf2f(A[idx]) + bf2f(Bb[idx]);
        s += x[k];
    }
    s = wave_sum64(s);
    float mean = s * (1.0f / DMODEL);
    float v = 0.f;
#pragma unroll
    for (int k = 0; k < 8; ++k) { float d = x[k] - mean; v += d * d; }
    v = wave_sum64(v) * (1.0f / DMODEL);
    float r = rsqrtf(v + 1e-5f);
#pragma unroll
    for (int k = 0; k < 8; ++k)
        out[row * DMODEL + k * 64 + lane] =
            f2bf((x[k] - mean) * r * g[k * 64 + lane] + be[k * 64 + lane]);
}

__global__ __launch_bounds__(64) void ln_double_kernel(
    const unsigned short* __restrict__ A, const unsigned short* __restrict__ Bb,
    const float* __restrict__ g2, const float* __restrict__ b2,
    const float* __restrict__ g3, const float* __restrict__ b3,
    unsigned short* __restrict__ out)
{
    const size_t row = blockIdx.x;
    const int lane = threadIdx.x;
    float x[8]; float s = 0.f;
#pragma unroll
    for (int k = 0; k < 8; ++k) {
        size_t idx = row * DMODEL + k * 64 + lane;
        x[k] = bf2f(A[idx]) + bf2f(Bb[idx]);
        s += x[k];
    }
    s = wave_sum64(s);
    float mean = s * (1.0f / DMODEL);
    float v = 0.f;
#pragma unroll
    for (int k = 0; k < 8; ++k) { float d = x[k] - mean; v += d * d; }
    v = wave_sum64(v) * (1.0f / DMODEL);
    float r = rsqrtf(v + 1e-5f);
    float t[8]; float s2 = 0.f;
#pragma unroll
    for (int k = 0; k < 8; ++k) {
        t[k] = (x[k] - mean) * r * g2[k * 64 + lane] + b2[k * 64 + lane];
        s2 += t[k];
    }
    s2 = wave_sum64(s2);
    float mean2 = s2 * (1.0f / DMODEL);
    float v2 = 0.f;
#pragma unroll
    for (int k = 0; k < 8; ++k) { float d = t[k] - mean2; v2 += d * d; }
    v2 = wave_sum64(v2) * (1.0f / DMODEL);
    float r2 = rsqrtf(v2 + 1e-5f);
#pragma unroll
    for (int k = 0; k < 8; ++k)
        out[row * DMODEL + k * 64 + lane] =
            f2bf((t[k] - mean2) * r2 * g3[k * 64 + lane] + b3[k * 64 + lane]);
}

// ---------------------------------------------------------------------------
// Mean-pool over S (bf16 in, fp32 atomics out) + tiny final GEMM (fp32).
// ---------------------------------------------------------------------------
__global__ __launch_bounds__(256) void pool_kernel(
    const unsigned short* __restrict__ h2, float* __restrict__ pooled)
{
    const int b = blockIdx.x >> 4;
    const int chunk = blockIdx.x & 15;
    const int tid = threadIdx.x;
    float s0 = 0.f, s1 = 0.f;
    size_t base = (size_t)(b * S_LEN + chunk * 128) * DMODEL;
    for (int r = 0; r < 128; ++r) {
        s0 += bf2f(h2[base + (size_t)r * DMODEL + tid]);
        s1 += bf2f(h2[base + (size_t)r * DMODEL + 256 + tid]);
    }
    atomicAdd(&pooled[b * DMODEL + tid], s0);
    atomicAdd(&pooled[b * DMODEL + 256 + tid], s1);
}

__global__ __launch_bounds__(128) void out_kernel(
    const float* __restrict__ pooled, const float* __restrict__ w,
    const float* __restrict__ bias, float* __restrict__ out)
{
    const int b = blockIdx.x;
    const int o = threadIdx.x;
    float acc = 0.f;
    for (int d = 0; d < DMODEL; ++d)
        acc += pooled[b * DMODEL + d] * w[d * 128 + o];
    out[b * 128 + o] = acc * (1.0f / S_LEN) + bias[o];
}

// ---------------------------------------------------------------------------
extern "C" void kernel_launch(void* const* d_in, const int* in_sizes, int n_in,
                              void* d_out, int out_size, void* d_ws, size_t ws_size,
                              hipStream_t stream)
{
    const float* x      = (const float*)d_in[0];
    const float* pos    = (const float*)d_in[1];
    const float* win_w  = (const float*)d_in[2];
    const float* win_b  = (const float*)d_in[3];
    const float* l_wqkv = (const float*)d_in[4];
    const float* l_bqkv = (const float*)d_in[5];
    const float* l_wo   = (const float*)d_in[6];
    const float* l_bo   = (const float*)d_in[7];
    const float* g_wqkv = (const float*)d_in[8];
    const float* g_bqkv = (const float*)d_in[9];
    const float* g_wo   = (const float*)d_in[10];
    const float* g_bo   = (const float*)d_in[11];
    const float* gate_w = (const float*)d_in[12];
    const float* gate_b = (const float*)d_in[13];
    const float* ffn_w1 = (const float*)d_in[14];
    const float* ffn_b1 = (const float*)d_in[15];
    const float* ffn_w2 = (const float*)d_in[16];
    const float* ffn_b2 = (const float*)d_in[17];
    const float* n1_g   = (const float*)d_in[18];
    const float* n1_b   = (const float*)d_in[19];
    const float* n2_g   = (const float*)d_in[20];
    const float* n2_b   = (const float*)d_in[21];
    const float* n3_g   = (const float*)d_in[22];
    const float* n3_b   = (const float*)d_in[23];
    const float* out_w  = (const float*)d_in[24];
    const float* out_b  = (const float*)d_in[25];
    float* out = (float*)d_out;

    unsigned short* ws16 = (unsigned short*)d_ws;
    const size_t UA = (size_t)M_ROWS * DMODEL;   // 4.19M bf16 = 8 MiB
    unsigned short* H  = ws16 + 0 * UA;
    unsigned short* Qb = ws16 + 1 * UA;
    unsigned short* Kb = ws16 + 2 * UA;
    unsigned short* Vb = ws16 + 3 * UA;
    unsigned short* AO = ws16 + 4 * UA;
    unsigned short* LO = ws16 + 5 * UA;
    unsigned short* GO     = Qb;            // Q dead after global attn
    unsigned short* FUSED  = Kb;            // K dead after global attn
    unsigned short* H1     = Vb;            // V dead after global attn
    unsigned short* FFNMID = AO;            // spans units 4..5 (AO+LO dead)
    unsigned short* FFNOUT = Qb;            // GO dead after gate
    unsigned short* H2     = Kb;            // FUSED dead after LN1
    float* POOLED = (float*)(void*)H;       // H dead after LN1

    // transposed bf16 weights
    unsigned short* wt = ws16 + 6 * UA;
    unsigned short* win_t  = wt;                      // 512 x 256
    unsigned short* lqkv_t = win_t  + 131072;         // 3 x (512 x 512)
    unsigned short* lwo_t  = lqkv_t + 786432;
    unsigned short* gqkv_t = lwo_t  + 262144;
    unsigned short* gwo_t  = gqkv_t + 786432;
    unsigned short* gate_t = gwo_t  + 262144;         // 512 x 1024
    unsigned short* ffn1_t = gate_t + 524288;         // 1024 x 512
    unsigned short* ffn2_t = ffn1_t + 524288;         // 512 x 1024

    dim3 blk(256);
    wcast_kernel<<<dim3(8, 16, 1),  blk, 0, stream>>>(win_w,  win_t,  256, 512);
    wcast_kernel<<<dim3(16, 16, 3), blk, 0, stream>>>(l_wqkv, lqkv_t, 512, 512);
    wcast_kernel<<<dim3(16, 16, 1), blk, 0, stream>>>(l_wo,   lwo_t,  512, 512);
    wcast_kernel<<<dim3(16, 16, 3), blk, 0, stream>>>(g_wqkv, gqkv_t, 512, 512);
    wcast_kernel<<<dim3(16, 16, 1), blk, 0, stream>>>(g_wo,   gwo_t,  512, 512);
    wcast_kernel<<<dim3(32, 16, 1), blk, 0, stream>>>(gate_w, gate_t, 1024, 512);
    wcast_kernel<<<dim3(16, 32, 1), blk, 0, stream>>>(ffn_w1, ffn1_t, 512, 1024);
    wcast_kernel<<<dim3(32, 16, 1), blk, 0, stream>>>(ffn_w2, ffn2_t, 1024, 512);

    dim3 gD(M_ROWS / 128, 512 / 64);     // 64 x 8
    dim3 gF(M_ROWS / 128, 1024 / 64);    // 64 x 16
    dim3 gA(S_LEN / 64, NHEAD, BATCH);   // 32 x 8 x 4

    // h = x @ win_w + win_b + pos
    gemm_mfma<1><<<gD, blk, 0, stream>>>(x, nullptr, win_t, win_b, pos, H, M_ROWS, 512, 256);

    // local path
    gemm_mfma<0><<<gD, blk, 0, stream>>>(H, nullptr, lqkv_t + 0 * 262144, l_bqkv + 0 * 512, nullptr, Qb, M_ROWS, 512, 512);
    gemm_mfma<0><<<gD, blk, 0, stream>>>(H, nullptr, lqkv_t + 1 * 262144, l_bqkv + 1 * 512, nullptr, Kb, M_ROWS, 512, 512);
    gemm_mfma<0><<<gD, blk, 0, stream>>>(H, nullptr, lqkv_t + 2 * 262144, l_bqkv + 2 * 512, nullptr, Vb, M_ROWS, 512, 512);
    attn_mfma<<<gA, blk, 0, stream>>>(Qb, Kb, Vb, AO, 1);
    gemm_mfma<0><<<gD, blk, 0, stream>>>(AO, nullptr, lwo_t, l_bo, nullptr, LO, M_ROWS, 512, 512);

    // global path
    gemm_mfma<0><<<gD, blk, 0, stream>>>(H, nullptr, gqkv_t + 0 * 262144, g_bqkv + 0 * 512, nullptr, Qb, M_ROWS, 512, 512);
    gemm_mfma<0><<<gD, blk, 0, stream>>>(H, nullptr, gqkv_t + 1 * 262144, g_bqkv + 1 * 512, nullptr, Kb, M_ROWS, 512, 512);
    gemm_mfma<0><<<gD, blk, 0, stream>>>(H, nullptr, gqkv_t + 2 * 262144, g_bqkv + 2 * 512, nullptr, Vb, M_ROWS, 512, 512);
    attn_mfma<<<gA, blk, 0, stream>>>(Qb, Kb, Vb, AO, 0);
    gemm_mfma<0><<<gD, blk, 0, stream>>>(AO, nullptr, gwo_t, g_bo, nullptr, GO, M_ROWS, 512, 512);

    // gate + fuse
    gemm_mfma<3><<<gD, blk, 0, stream>>>(LO, GO, gate_t, gate_b, nullptr, FUSED, M_ROWS, 512, 1024);

    // h1 = LN(h + fused)
    ln_res_kernel<<<M_ROWS, 64, 0, stream>>>(H, FUSED, n1_g, n1_b, H1);

    // FFN
    gemm_mfma<2><<<gF, blk, 0, stream>>>(H1, nullptr, ffn1_t, ffn_b1, nullptr, FFNMID, M_ROWS, 1024, 512);
    gemm_mfma<0><<<gD, blk, 0, stream>>>(FFNMID, nullptr, ffn2_t, ffn_b2, nullptr, FFNOUT, M_ROWS, 512, 1024);

    // h2 = LN(LN(h1 + ffn, n2), n3)
    ln_double_kernel<<<M_ROWS, 64, 0, stream>>>(H1, FFNOUT, n2_g, n2_b, n3_g, n3_b, H2);

    // pool + final projection
    hipMemsetAsync(POOLED, 0, BATCH * DMODEL * sizeof(float), stream);
    pool_kernel<<<dim3(BATCH * 16), blk, 0, stream>>>(H2, POOLED);
    out_kernel<<<dim3(BATCH), dim3(128), 0, stream>>>(POOLED, out_w, out_b, out);
}

// Round 3
// 442.453 us; speedup vs baseline: 3.6019x; 1.1172x over previous
//
#include <hip/hip_runtime.h>
#include <math.h>

#define S_LEN 2048
#define DMODEL 512
#define NHEAD 8
#define BATCH 4
#define M_ROWS (BATCH * S_LEN)   // 8192

typedef __attribute__((ext_vector_type(8))) short frag8;   // 8 bf16 (4 VGPRs)
typedef __attribute__((ext_vector_type(4))) float f32x4;   // MFMA accumulator

__device__ inline unsigned short f2bf(float f) {
    unsigned int u = __float_as_uint(f);
    return (unsigned short)((u + 0x7FFFu + ((u >> 16) & 1u)) >> 16);  // RNE
}
__device__ inline float bf2f(unsigned short h) {
    return __uint_as_float(((unsigned int)h) << 16);
}

// ---------------------------------------------------------------------------
// Weight transpose + cast: W(K,N) fp32 -> Wt(N,K) bf16.  grid (K/32, N/32, batch)
// ---------------------------------------------------------------------------
__global__ __launch_bounds__(256) void wcast_kernel(
    const float* __restrict__ W, unsigned short* __restrict__ Wt, int K, int N)
{
    __shared__ float t[32][33];
    const int k0 = blockIdx.x * 32, n0 = blockIdx.y * 32;
    const float* Wb = W + (size_t)blockIdx.z * K * N;
    unsigned short* Wtb = Wt + (size_t)blockIdx.z * K * N;
    {
        int kk = threadIdx.x >> 3, nq = (threadIdx.x & 7) * 4;
        float4 v = *(const float4*)&Wb[(size_t)(k0 + kk) * N + n0 + nq];
        t[kk][nq + 0] = v.x; t[kk][nq + 1] = v.y; t[kk][nq + 2] = v.z; t[kk][nq + 3] = v.w;
    }
    __syncthreads();
    {
        int n = threadIdx.x >> 3, kq = (threadIdx.x & 7) * 4;
        ushort4 o;
        o.x = f2bf(t[kq + 0][n]); o.y = f2bf(t[kq + 1][n]);
        o.z = f2bf(t[kq + 2][n]); o.w = f2bf(t[kq + 3][n]);
        *(ushort4*)&Wtb[(size_t)(n0 + n) * K + k0 + kq] = o;
    }
}

// ---------------------------------------------------------------------------
// MFMA GEMM: C(M,N) bf16 = A(M,K) @ Wt(N,K)^T + bias(fp32), epilogue by MODE.
//   MODE 0: bias            MODE 1: bias + pos  (A is fp32)
//   MODE 2: relu(bias+acc)  MODE 3: gate blend (A=LO bf16, A2=GO bf16, K=1024)
//   MODE 4: (bias+acc)*0.125   (Q projection; folds attention scale)
// BM=128, BN=64, BK=64; 256 threads = 4 waves; wave tile 64x32 (4x2 MFMA tiles).
// ---------------------------------------------------------------------------
template <int MODE>
__global__ __launch_bounds__(256) void gemm_mfma(
    const void* __restrict__ Av, const unsigned short* __restrict__ A2,
    const unsigned short* __restrict__ Wt, const float* __restrict__ bias,
    const float* __restrict__ pos, unsigned short* __restrict__ C,
    int M, int N, int K)
{
    __shared__ unsigned short As[128][72];   // [m][k], stride 144 B (16B-aligned)
    __shared__ unsigned short Bs[64][72];    // [n][k]
    const int tid = threadIdx.x;
    const int wave = tid >> 6, lane = tid & 63;
    const int lr = lane & 15, quad = lane >> 4, q8 = quad * 8;
    const int bm = blockIdx.x * 128, bn = blockIdx.y * 64;
    const int rm = (wave >> 1) * 64, rn = (wave & 1) * 32;
    const int Khalf = K >> 1;

    f32x4 acc[4][2];
#pragma unroll
    for (int t = 0; t < 4; ++t)
#pragma unroll
        for (int u = 0; u < 2; ++u) acc[t][u] = (f32x4){0.f, 0.f, 0.f, 0.f};

    for (int k0 = 0; k0 < K; k0 += 64) {
        __syncthreads();
        // ---- stage A tile (128 x 64) ----
        {
            const int m = tid >> 1, kh = (tid & 1) * 32;
            if constexpr (MODE == 1) {
                const float* src = (const float*)Av + (size_t)(bm + m) * K + k0 + kh;
#pragma unroll
                for (int i = 0; i < 4; ++i) {
                    float4 v0 = *(const float4*)(src + i * 8);
                    float4 v1 = *(const float4*)(src + i * 8 + 4);
                    unsigned short us[8];
                    us[0] = f2bf(v0.x); us[1] = f2bf(v0.y); us[2] = f2bf(v0.z); us[3] = f2bf(v0.w);
                    us[4] = f2bf(v1.x); us[5] = f2bf(v1.y); us[6] = f2bf(v1.z); us[7] = f2bf(v1.w);
                    *(uint4*)&As[m][kh + i * 8] = *(uint4*)us;
                }
            } else {
                const unsigned short* Ab = (const unsigned short*)Av;
                const int kk = k0 + kh;
                const unsigned short* src;
                if constexpr (MODE == 3)
                    src = (kk < Khalf) ? Ab + (size_t)(bm + m) * Khalf + kk
                                       : A2 + (size_t)(bm + m) * Khalf + (kk - Khalf);
                else
                    src = Ab + (size_t)(bm + m) * K + kk;
#pragma unroll
                for (int i = 0; i < 4; ++i)
                    *(uint4*)&As[m][kh + i * 8] = *(const uint4*)(src + i * 8);
            }
        }
        // ---- stage B tile (64 n x 64 k) from Wt[n][k] ----
        {
            const int n = tid >> 2, kq = (tid & 3) * 16;
            const unsigned short* src = Wt + (size_t)(bn + n) * K + k0 + kq;
            *(uint4*)&Bs[n][kq] = *(const uint4*)src;
            *(uint4*)&Bs[n][kq + 8] = *(const uint4*)(src + 8);
        }
        __syncthreads();
        // ---- MFMA: 2 k-chunks of 32 ----
#pragma unroll
        for (int kc = 0; kc < 2; ++kc) {
            frag8 af[4], bfr[2];
#pragma unroll
            for (int t = 0; t < 4; ++t)
                af[t] = *(const frag8*)&As[rm + t * 16 + lr][kc * 32 + q8];
#pragma unroll
            for (int u = 0; u < 2; ++u)
                bfr[u] = *(const frag8*)&Bs[rn + u * 16 + lr][kc * 32 + q8];
#pragma unroll
            for (int t = 0; t < 4; ++t)
#pragma unroll
                for (int u = 0; u < 2; ++u)
                    acc[t][u] = __builtin_amdgcn_mfma_f32_16x16x32_bf16(
                        af[t], bfr[u], acc[t][u], 0, 0, 0);
        }
    }

    // ---- epilogue ----
#pragma unroll
    for (int t = 0; t < 4; ++t) {
#pragma unroll
        for (int i = 0; i < 4; ++i) {
            const int m = bm + rm + t * 16 + quad * 4 + i;
#pragma unroll
            for (int u = 0; u < 2; ++u) {
                const int n = bn + rn + u * 16 + lr;
                float v = acc[t][u][i] + bias[n];
                if constexpr (MODE == 1) v += pos[(size_t)(m & (S_LEN - 1)) * N + n];
                if constexpr (MODE == 2) v = fmaxf(v, 0.0f);
                if constexpr (MODE == 4) v *= 0.125f;
                if constexpr (MODE == 3) {
                    float g = tanhf(fmaxf(v, 0.0f));
                    float lo = bf2f(((const unsigned short*)Av)[(size_t)m * Khalf + n]);
                    float go = bf2f(A2[(size_t)m * Khalf + n]);
                    v = g * lo + (1.0f - g) * go;
                }
                C[(size_t)m * N + n] = f2bf(v);
            }
        }
    }
}

// ---------------------------------------------------------------------------
// MFMA flash attention, max-free softmax (scores are O(1); exp cannot overflow;
// scale 1/8 pre-folded into Q). Q,K,V,O: (B,S,D) bf16, head slice h*64.
// Block = 256 thr = 4 waves; wave handles 16 q-rows; 64x64 tiles.
// Ps is wave-private (wave w touches only rows [16w,16w+16)) and doubles as
// the Q staging buffer. l_i reduced across lanes ONCE after the kt loop.
// ---------------------------------------------------------------------------
__global__ __launch_bounds__(256) void attn_mfma(
    const unsigned short* __restrict__ Q, const unsigned short* __restrict__ Kv,
    const unsigned short* __restrict__ Vv, unsigned short* __restrict__ O, int masked)
{
    __shared__ unsigned short Ks[64][72];   // [c][d]
    __shared__ unsigned short Vts[64][72];  // [d][c]
    __shared__ unsigned short Ps[64][72];   // [q][c]; also Q staging [q][d]
    const int qt = blockIdx.x, h = blockIdx.y, b = blockIdx.z;
    const int tid = threadIdx.x;
    const int wave = tid >> 6, lane = tid & 63;
    const int lr = lane & 15, quad = lane >> 4, q8 = quad * 8;

    // stage Q (each wave its own 16 rows) and hoist the loop-invariant frags
    {
        const int q = tid >> 2, d0 = (tid & 3) * 16;
        const unsigned short* src = Q + ((size_t)(b * S_LEN + qt * 64 + q) * DMODEL + h * 64 + d0);
        *(uint4*)&Ps[q][d0] = *(const uint4*)src;
        *(uint4*)&Ps[q][d0 + 8] = *(const uint4*)(src + 8);
    }
    frag8 qf[2];
    qf[0] = *(const frag8*)&Ps[wave * 16 + lr][q8];
    qf[1] = *(const frag8*)&Ps[wave * 16 + lr][32 + q8];

    f32x4 oacc[4];
#pragma unroll
    for (int t = 0; t < 4; ++t) oacc[t] = (f32x4){0.f, 0.f, 0.f, 0.f};
    float l_i[4] = {0.f, 0.f, 0.f, 0.f};

    int kt0 = 0, kt1 = S_LEN / 64 - 1;
    if (masked) { kt0 = qt > 0 ? qt - 1 : 0; kt1 = qt < 31 ? qt + 1 : 31; }

    for (int kt = kt0; kt <= kt1; ++kt) {
        __syncthreads();   // protect Ks/Vts against previous iteration's readers
        {   // stage K (as [c][d]) and V transposed (as [d][c])
            const int c = tid >> 2, d0 = (tid & 3) * 16;
            const unsigned short* ksrc = Kv + ((size_t)(b * S_LEN + kt * 64 + c) * DMODEL + h * 64 + d0);
            *(uint4*)&Ks[c][d0] = *(const uint4*)ksrc;
            *(uint4*)&Ks[c][d0 + 8] = *(const uint4*)(ksrc + 8);
            const unsigned short* vsrc = Vv + ((size_t)(b * S_LEN + kt * 64 + c) * DMODEL + h * 64 + d0);
            unsigned short vb[16];
            *(uint4*)&vb[0] = *(const uint4*)vsrc;
            *(uint4*)&vb[8] = *(const uint4*)(vsrc + 8);
#pragma unroll
            for (int j = 0; j < 16; ++j) Vts[d0 + j][c] = vb[j];
        }
        __syncthreads();

        // ---- S = Q K^T (Q pre-scaled by 1/8) ----
        f32x4 sacc[4];
#pragma unroll
        for (int t = 0; t < 4; ++t) sacc[t] = (f32x4){0.f, 0.f, 0.f, 0.f};
#pragma unroll
        for (int kc = 0; kc < 2; ++kc) {
#pragma unroll
            for (int t = 0; t < 4; ++t) {
                frag8 bb = *(const frag8*)&Ks[t * 16 + lr][kc * 32 + q8];
                sacc[t] = __builtin_amdgcn_mfma_f32_16x16x32_bf16(qf[kc], bb, sacc[t], 0, 0, 0);
            }
        }

        // ---- max-free softmax: p = exp(s); per-lane partial row sums ----
#pragma unroll
        for (int i = 0; i < 4; ++i) {
            float p[4];
#pragma unroll
            for (int t = 0; t < 4; ++t) p[t] = __expf(sacc[t][i]);
            if (masked) {
                const int qa = qt * 64 + wave * 16 + quad * 4 + i;
                const int ca = kt * 64 + lr;
#pragma unroll
                for (int t = 0; t < 4; ++t) {
                    const int d = qa - (ca + t * 16);
                    if (d > 32 || d < -32) p[t] = 0.f;
                }
            }
            l_i[i] += (p[0] + p[1]) + (p[2] + p[3]);
#pragma unroll
            for (int t = 0; t < 4; ++t)
                Ps[wave * 16 + quad * 4 + i][t * 16 + lr] = f2bf(p[t]);
        }
        // NOTE: no barrier — Ps rows [16w,16w+16) are written and read only by wave w.

        // ---- O += P V ----
#pragma unroll
        for (int cc = 0; cc < 2; ++cc) {
            frag8 a = *(const frag8*)&Ps[wave * 16 + lr][cc * 32 + q8];
#pragma unroll
            for (int t = 0; t < 4; ++t) {
                frag8 bb = *(const frag8*)&Vts[t * 16 + lr][cc * 32 + q8];
                oacc[t] = __builtin_amdgcn_mfma_f32_16x16x32_bf16(a, bb, oacc[t], 0, 0, 0);
            }
        }
    }

    // ---- single deferred row-sum reduction + epilogue ----
#pragma unroll
    for (int i = 0; i < 4; ++i) {
        float r = l_i[i];
        r += __shfl_xor(r, 1); r += __shfl_xor(r, 2);
        r += __shfl_xor(r, 4); r += __shfl_xor(r, 8);
        const float inv = 1.0f / r;
        const int q = qt * 64 + wave * 16 + quad * 4 + i;
#pragma unroll
        for (int t = 0; t < 4; ++t)
            O[(size_t)(b * S_LEN + q) * DMODEL + h * 64 + t * 16 + lr] = f2bf(oacc[t][i] * inv);
    }
}

// ---------------------------------------------------------------------------
// LayerNorm (bf16 in/out, fp32 math): one wave per row of 512.
// ---------------------------------------------------------------------------
__device__ inline float wave_sum64(float v) {
#pragma unroll
    for (int off = 1; off < 64; off <<= 1) v += __shfl_xor(v, off);
    return v;
}

__global__ __launch_bounds__(64) void ln_res_kernel(
    const unsigned short* __restrict__ A, const unsigned short* __restrict__ Bb,
    const float* __restrict__ g, const float* __restrict__ be,
    unsigned short* __restrict__ out)
{
    const size_t row = blockIdx.x;
    const int lane = threadIdx.x;
    float x[8]; float s = 0.f;
#pragma unroll
    for (int k = 0; k < 8; ++k) {
        size_t idx = row * DMODEL + k * 64 + lane;
        x[k] = bf2f(A[idx]) + bf2f(Bb[idx]);
        s += x[k];
    }
    s = wave_sum64(s);
    float mean = s * (1.0f / DMODEL);
    float v = 0.f;
#pragma unroll
    for (int k = 0; k < 8; ++k) { float d = x[k] - mean; v += d * d; }
    v = wave_sum64(v) * (1.0f / DMODEL);
    float r = rsqrtf(v + 1e-5f);
#pragma unroll
    for (int k = 0; k < 8; ++k)
        out[row * DMODEL + k * 64 + lane] =
            f2bf((x[k] - mean) * r * g[k * 64 + lane] + be[k * 64 + lane]);
}

__global__ __launch_bounds__(64) void ln_double_kernel(
    const unsigned short* __restrict__ A, const unsigned short* __restrict__ Bb,
    const float* __restrict__ g2, const float* __restrict__ b2,
    const float* __restrict__ g3, const float* __restrict__ b3,
    unsigned short* __restrict__ out)
{
    const size_t row = blockIdx.x;
    const int lane = threadIdx.x;
    float x[8]; float s = 0.f;
#pragma unroll
    for (int k = 0; k < 8; ++k) {
        size_t idx = row * DMODEL + k * 64 + lane;
        x[k] = bf2f(A[idx]) + bf2f(Bb[idx]);
        s += x[k];
    }
    s = wave_sum64(s);
    float mean = s * (1.0f / DMODEL);
    float v = 0.f;
#pragma unroll
    for (int k = 0; k < 8; ++k) { float d = x[k] - mean; v += d * d; }
    v = wave_sum64(v) * (1.0f / DMODEL);
    float r = rsqrtf(v + 1e-5f);
    float t[8]; float s2 = 0.f;
#pragma unroll
    for (int k = 0; k < 8; ++k) {
        t[k] = (x[k] - mean) * r * g2[k * 64 + lane] + b2[k * 64 + lane];
        s2 += t[k];
    }
    s2 = wave_sum64(s2);
    float mean2 = s2 * (1.0f / DMODEL);
    float v2 = 0.f;
#pragma unroll
    for (int k = 0; k < 8; ++k) { float d = t[k] - mean2; v2 += d * d; }
    v2 = wave_sum64(v2) * (1.0f / DMODEL);
    float r2 = rsqrtf(v2 + 1e-5f);
#pragma unroll
    for (int k = 0; k < 8; ++k)
        out[row * DMODEL + k * 64 + lane] =
            f2bf((t[k] - mean2) * r2 * g3[k * 64 + lane] + b3[k * 64 + lane]);
}

// ---------------------------------------------------------------------------
// Mean-pool over S (bf16 in, fp32 atomics out) + tiny final GEMM (fp32).
// ---------------------------------------------------------------------------
__global__ __launch_bounds__(256) void pool_kernel(
    const unsigned short* __restrict__ h2, float* __restrict__ pooled)
{
    const int b = blockIdx.x >> 4;
    const int chunk = blockIdx.x & 15;
    const int tid = threadIdx.x;
    float s0 = 0.f, s1 = 0.f;
    size_t base = (size_t)(b * S_LEN + chunk * 128) * DMODEL;
    for (int r = 0; r < 128; ++r) {
        s0 += bf2f(h2[base + (size_t)r * DMODEL + tid]);
        s1 += bf2f(h2[base + (size_t)r * DMODEL + 256 + tid]);
    }
    atomicAdd(&pooled[b * DMODEL + tid], s0);
    atomicAdd(&pooled[b * DMODEL + 256 + tid], s1);
}

__global__ __launch_bounds__(128) void out_kernel(
    const float* __restrict__ pooled, const float* __restrict__ w,
    const float* __restrict__ bias, float* __restrict__ out)
{
    const int b = blockIdx.x;
    const int o = threadIdx.x;
    float acc = 0.f;
    for (int d = 0; d < DMODEL; ++d)
        acc += pooled[b * DMODEL + d] * w[d * 128 + o];
    out[b * 128 + o] = acc * (1.0f / S_LEN) + bias[o];
}

// ---------------------------------------------------------------------------
extern "C" void kernel_launch(void* const* d_in, const int* in_sizes, int n_in,
                              void* d_out, int out_size, void* d_ws, size_t ws_size,
                              hipStream_t stream)
{
    const float* x      = (const float*)d_in[0];
    const float* pos    = (const float*)d_in[1];
    const float* win_w  = (const float*)d_in[2];
    const float* win_b  = (const float*)d_in[3];
    const float* l_wqkv = (const float*)d_in[4];
    const float* l_bqkv = (const float*)d_in[5];
    const float* l_wo   = (const float*)d_in[6];
    const float* l_bo   = (const float*)d_in[7];
    const float* g_wqkv = (const float*)d_in[8];
    const float* g_bqkv = (const float*)d_in[9];
    const float* g_wo   = (const float*)d_in[10];
    const float* g_bo   = (const float*)d_in[11];
    const float* gate_w = (const float*)d_in[12];
    const float* gate_b = (const float*)d_in[13];
    const float* ffn_w1 = (const float*)d_in[14];
    const float* ffn_b1 = (const float*)d_in[15];
    const float* ffn_w2 = (const float*)d_in[16];
    const float* ffn_b2 = (const float*)d_in[17];
    const float* n1_g   = (const float*)d_in[18];
    const float* n1_b   = (const float*)d_in[19];
    const float* n2_g   = (const float*)d_in[20];
    const float* n2_b   = (const float*)d_in[21];
    const float* n3_g   = (const float*)d_in[22];
    const float* n3_b   = (const float*)d_in[23];
    const float* out_w  = (const float*)d_in[24];
    const float* out_b  = (const float*)d_in[25];
    float* out = (float*)d_out;

    unsigned short* ws16 = (unsigned short*)d_ws;
    const size_t UA = (size_t)M_ROWS * DMODEL;   // 4.19M bf16 = 8 MiB
    unsigned short* H  = ws16 + 0 * UA;
    unsigned short* Qb = ws16 + 1 * UA;
    unsigned short* Kb = ws16 + 2 * UA;
    unsigned short* Vb = ws16 + 3 * UA;
    unsigned short* AO = ws16 + 4 * UA;
    unsigned short* LO = ws16 + 5 * UA;
    unsigned short* GO     = Qb;            // Q dead after global attn
    unsigned short* FUSED  = Kb;            // K dead after global attn
    unsigned short* H1     = Vb;            // V dead after global attn
    unsigned short* FFNMID = AO;            // spans units 4..5 (AO+LO dead)
    unsigned short* FFNOUT = Qb;            // GO dead after gate
    unsigned short* H2     = Kb;            // FUSED dead after LN1
    float* POOLED = (float*)(void*)H;       // H dead after LN1

    // transposed bf16 weights
    unsigned short* wt = ws16 + 6 * UA;
    unsigned short* win_t  = wt;                      // 512 x 256
    unsigned short* lqkv_t = win_t  + 131072;         // 3 x (512 x 512)
    unsigned short* lwo_t  = lqkv_t + 786432;
    unsigned short* gqkv_t = lwo_t  + 262144;
    unsigned short* gwo_t  = gqkv_t + 786432;
    unsigned short* gate_t = gwo_t  + 262144;         // 512 x 1024
    unsigned short* ffn1_t = gate_t + 524288;         // 1024 x 512
    unsigned short* ffn2_t = ffn1_t + 524288;         // 512 x 1024

    dim3 blk(256);
    wcast_kernel<<<dim3(8, 16, 1),  blk, 0, stream>>>(win_w,  win_t,  256, 512);
    wcast_kernel<<<dim3(16, 16, 3), blk, 0, stream>>>(l_wqkv, lqkv_t, 512, 512);
    wcast_kernel<<<dim3(16, 16, 1), blk, 0, stream>>>(l_wo,   lwo_t,  512, 512);
    wcast_kernel<<<dim3(16, 16, 3), blk, 0, stream>>>(g_wqkv, gqkv_t, 512, 512);
    wcast_kernel<<<dim3(16, 16, 1), blk, 0, stream>>>(g_wo,   gwo_t,  512, 512);
    wcast_kernel<<<dim3(32, 16, 1), blk, 0, stream>>>(gate_w, gate_t, 1024, 512);
    wcast_kernel<<<dim3(16, 32, 1), blk, 0, stream>>>(ffn_w1, ffn1_t, 512, 1024);
    wcast_kernel<<<dim3(32, 16, 1), blk, 0, stream>>>(ffn_w2, ffn2_t, 1024, 512);

    dim3 gD(M_ROWS / 128, 512 / 64);     // 64 x 8
    dim3 gF(M_ROWS / 128, 1024 / 64);    // 64 x 16
    dim3 gA(S_LEN / 64, NHEAD, BATCH);   // 32 x 8 x 4

    // h = x @ win_w + win_b + pos
    gemm_mfma<1><<<gD, blk, 0, stream>>>(x, nullptr, win_t, win_b, pos, H, M_ROWS, 512, 256);

    // local path (Q projection pre-scaled by 1/8 via MODE 4)
    gemm_mfma<4><<<gD, blk, 0, stream>>>(H, nullptr, lqkv_t + 0 * 262144, l_bqkv + 0 * 512, nullptr, Qb, M_ROWS, 512, 512);
    gemm_mfma<0><<<gD, blk, 0, stream>>>(H, nullptr, lqkv_t + 1 * 262144, l_bqkv + 1 * 512, nullptr, Kb, M_ROWS, 512, 512);
    gemm_mfma<0><<<gD, blk, 0, stream>>>(H, nullptr, lqkv_t + 2 * 262144, l_bqkv + 2 * 512, nullptr, Vb, M_ROWS, 512, 512);
    attn_mfma<<<gA, blk, 0, stream>>>(Qb, Kb, Vb, AO, 1);
    gemm_mfma<0><<<gD, blk, 0, stream>>>(AO, nullptr, lwo_t, l_bo, nullptr, LO, M_ROWS, 512, 512);

    // global path
    gemm_mfma<4><<<gD, blk, 0, stream>>>(H, nullptr, gqkv_t + 0 * 262144, g_bqkv + 0 * 512, nullptr, Qb, M_ROWS, 512, 512);
    gemm_mfma<0><<<gD, blk, 0, stream>>>(H, nullptr, gqkv_t + 1 * 262144, g_bqkv + 1 * 512, nullptr, Kb, M_ROWS, 512, 512);
    gemm_mfma<0><<<gD, blk, 0, stream>>>(H, nullptr, gqkv_t + 2 * 262144, g_bqkv + 2 * 512, nullptr, Vb, M_ROWS, 512, 512);
    attn_mfma<<<gA, blk, 0, stream>>>(Qb, Kb, Vb, AO, 0);
    gemm_mfma<0><<<gD, blk, 0, stream>>>(AO, nullptr, gwo_t, g_bo, nullptr, GO, M_ROWS, 512, 512);

    // gate + fuse
    gemm_mfma<3><<<gD, blk, 0, stream>>>(LO, GO, gate_t, gate_b, nullptr, FUSED, M_ROWS, 512, 1024);

    // h1 = LN(h + fused)
    ln_res_kernel<<<M_ROWS, 64, 0, stream>>>(H, FUSED, n1_g, n1_b, H1);

    // FFN
    gemm_mfma<2><<<gF, blk, 0, stream>>>(H1, nullptr, ffn1_t, ffn_b1, nullptr, FFNMID, M_ROWS, 1024, 512);
    gemm_mfma<0><<<gD, blk, 0, stream>>>(FFNMID, nullptr, ffn2_t, ffn_b2, nullptr, FFNOUT, M_ROWS, 512, 1024);

    // h2 = LN(LN(h1 + ffn, n2), n3)
    ln_double_kernel<<<M_ROWS, 64, 0, stream>>>(H1, FFNOUT, n2_g, n2_b, n3_g, n3_b, H2);

    // pool + final projection
    hipMemsetAsync(POOLED, 0, BATCH * DMODEL * sizeof(float), stream);
    pool_kernel<<<dim3(BATCH * 16), blk, 0, stream>>>(H2, POOLED);
    out_kernel<<<dim3(BATCH), dim3(128), 0, stream>>>(POOLED, out_w, out_b, out);
}